// Round 1
// baseline (261.621 us; speedup 1.0000x reference)
//
#include <hip/hip_runtime.h>

#define N_NODES 16384
#define IN_F 128
#define OUT_F 128
#define NE 524288
#define WORDS 512          // 16384 bits / 32 per row
#define CDIM 1152          // IN_F*NG + IN_F

typedef unsigned int uint32;

// ---------------- weight transpose: Wt[c*128+o] ----------------
__global__ __launch_bounds__(256) void transw_kernel(
    const float* __restrict__ sw, const float* __restrict__ bw,
    float* __restrict__ Wt) {
    int idx = blockIdx.x * 256 + threadIdx.x;      // 0 .. 1152*128-1
    int c = idx >> 7, o = idx & 127;
    float v = (c < 1024) ? sw[o * 1024 + c] : bw[o * 128 + (c - 1024)];
    Wt[idx] = v;
}

// ---------------- edge scatter into bitmask ----------------
__global__ __launch_bounds__(256) void scatter_kernel(
    const int* __restrict__ ei, uint32* __restrict__ bm) {
    int e = blockIdx.x * 256 + threadIdx.x;
    int a = ei[e];
    int b = ei[NE + e];
    atomicOr(bm + (size_t)a * WORDS + (b >> 5), 1u << (b & 31));
    atomicOr(bm + (size_t)b * WORDS + (a >> 5), 1u << (a & 31));
}

// ---------------- degree -> dis = rsqrt(deg) ----------------
__global__ __launch_bounds__(256) void deg_kernel(
    const uint32* __restrict__ bm, float* __restrict__ dis) {
    const int lane = threadIdx.x & 63;
    const int row = blockIdx.x * 4 + (threadIdx.x >> 6);
    const uint32* r = bm + (size_t)row * WORDS;
    int s = 0;
#pragma unroll
    for (int q = 0; q < 8; ++q) s += __popc(r[lane + 64 * q]);
#pragma unroll
    for (int o = 32; o; o >>= 1) s += __shfl_xor(s, o);
    if (lane == 0) dis[row] = rsqrtf((float)s);
}

// ---------------- FastKAN support, pre-scaled by dis ----------------
// block = 128 threads, 8 nodes per block
__global__ __launch_bounds__(128) void support_kernel(
    const float* __restrict__ x, const float* __restrict__ gamma,
    const float* __restrict__ beta, const float* __restrict__ Wt,
    const float* __restrict__ base_b, const float* __restrict__ dis,
    float* __restrict__ Ssc) {
    __shared__ float Bs[8][CDIM];
    const int lane = threadIdx.x & 63;
    const int wv = threadIdx.x >> 6;     // 0..1
    const int nodeBase = blockIdx.x * 8;

    const float g0 = gamma[lane], g1 = gamma[lane + 64];
    const float be0 = beta[lane], be1 = beta[lane + 64];

    for (int n = wv * 4; n < wv * 4 + 4; ++n) {
        const int row = nodeBase + n;
        float f0 = x[(size_t)row * 128 + lane];
        float f1 = x[(size_t)row * 128 + lane + 64];
        float s = f0 + f1;
#pragma unroll
        for (int o = 32; o; o >>= 1) s += __shfl_xor(s, o);
        float mu = s * 0.0078125f;
        float d0 = f0 - mu, d1 = f1 - mu;
        float v = d0 * d0 + d1 * d1;
#pragma unroll
        for (int o = 32; o; o >>= 1) v += __shfl_xor(v, o);
        float rstd = rsqrtf(v * 0.0078125f + 1e-5f);
        float h0 = d0 * rstd * g0 + be0;
        float h1 = d1 * rstd * g1 + be1;
#pragma unroll
        for (int g = 0; g < 8; ++g) {
            float gv = -2.0f + (float)g * (4.0f / 7.0f);
            float z0 = (h0 - gv) * 1.75f;       // /denom, denom = 4/7
            float z1 = (h1 - gv) * 1.75f;
            Bs[n][lane * 8 + g] = __expf(-z0 * z0);
            Bs[n][(lane + 64) * 8 + g] = __expf(-z1 * z1);
        }
        Bs[n][1024 + lane]      = f0 / (1.0f + __expf(-f0));
        Bs[n][1024 + lane + 64] = f1 / (1.0f + __expf(-f1));
    }
    __syncthreads();

    // GEMM: 8 nodes x 128 outs; thread = (tn: 2 nodes, to: 4 outs)
    const int to = threadIdx.x & 31;
    const int tn = threadIdx.x >> 5;      // 0..3
    const int o0 = to * 4;
    const int n0 = tn * 2;
    float acc0[4] = {0.f, 0.f, 0.f, 0.f};
    float acc1[4] = {0.f, 0.f, 0.f, 0.f};

    for (int c = 0; c < CDIM; c += 4) {
        float4 w[4];
#pragma unroll
        for (int q = 0; q < 4; ++q)
            w[q] = *(const float4*)(Wt + (size_t)(c + q) * 128 + o0);
        float4 a4 = *(const float4*)(&Bs[n0][c]);
        float4 b4 = *(const float4*)(&Bs[n0 + 1][c]);
        float av[4] = {a4.x, a4.y, a4.z, a4.w};
        float bv[4] = {b4.x, b4.y, b4.z, b4.w};
#pragma unroll
        for (int q = 0; q < 4; ++q) {
            acc0[0] += av[q] * w[q].x; acc0[1] += av[q] * w[q].y;
            acc0[2] += av[q] * w[q].z; acc0[3] += av[q] * w[q].w;
            acc1[0] += bv[q] * w[q].x; acc1[1] += bv[q] * w[q].y;
            acc1[2] += bv[q] * w[q].z; acc1[3] += bv[q] * w[q].w;
        }
    }

    const int row0 = nodeBase + n0;
    float di0 = dis[row0], di1 = dis[row0 + 1];
    float4 bb = *(const float4*)(base_b + o0);
    float4 r0, r1;
    r0.x = (acc0[0] + bb.x) * di0; r0.y = (acc0[1] + bb.y) * di0;
    r0.z = (acc0[2] + bb.z) * di0; r0.w = (acc0[3] + bb.w) * di0;
    r1.x = (acc1[0] + bb.x) * di1; r1.y = (acc1[1] + bb.y) * di1;
    r1.z = (acc1[2] + bb.z) * di1; r1.w = (acc1[3] + bb.w) * di1;
    *(float4*)(Ssc + (size_t)row0 * 128 + o0) = r0;
    *(float4*)(Ssc + (size_t)(row0 + 1) * 128 + o0) = r1;
}

// ---------------- aggregation: out[i] = dis_i * sum Ssc[nbr] + bias ----------------
__global__ __launch_bounds__(128) void aggregate_kernel(
    const uint32* __restrict__ bm, const float* __restrict__ Ssc,
    const float* __restrict__ dis, const float* __restrict__ bias,
    float* __restrict__ out) {
    __shared__ unsigned short lst[4096];
    __shared__ int cnts[128];
    const int t = threadIdx.x;
    const int i = blockIdx.x;

    uint4 w4 = ((const uint4*)(bm + (size_t)i * WORDS))[t];
    uint32 wsv[4] = {w4.x, w4.y, w4.z, w4.w};
    int myc = __popc(wsv[0]) + __popc(wsv[1]) + __popc(wsv[2]) + __popc(wsv[3]);
    cnts[t] = myc;
    __syncthreads();
    // Hillis-Steele inclusive scan over 128 entries (deterministic ordering)
#pragma unroll
    for (int off = 1; off < 128; off <<= 1) {
        int v = cnts[t];
        int add = (t >= off) ? cnts[t - off] : 0;
        __syncthreads();
        cnts[t] = v + add;
        __syncthreads();
    }
    int start = cnts[t] - myc;
    int total = cnts[127];
    if (total > 4096) total = 4096;

    int pos = start;
#pragma unroll
    for (int q = 0; q < 4; ++q) {
        uint32 w = wsv[q];
        int cbase = t * 128 + q * 32;
        while (w) {
            int b = __ffs(w) - 1;
            w &= w - 1;
            if (pos < 4096) lst[pos] = (unsigned short)(cbase + b);
            ++pos;
        }
    }
    __syncthreads();

    float acc = 0.0f;
    int base = 0;
    for (; base + 8 <= total; base += 8) {
        int j0 = lst[base + 0], j1 = lst[base + 1];
        int j2 = lst[base + 2], j3 = lst[base + 3];
        int j4 = lst[base + 4], j5 = lst[base + 5];
        int j6 = lst[base + 6], j7 = lst[base + 7];
        float a0 = Ssc[(size_t)j0 * 128 + t];
        float a1 = Ssc[(size_t)j1 * 128 + t];
        float a2 = Ssc[(size_t)j2 * 128 + t];
        float a3 = Ssc[(size_t)j3 * 128 + t];
        float a4 = Ssc[(size_t)j4 * 128 + t];
        float a5 = Ssc[(size_t)j5 * 128 + t];
        float a6 = Ssc[(size_t)j6 * 128 + t];
        float a7 = Ssc[(size_t)j7 * 128 + t];
        acc += ((a0 + a1) + (a2 + a3)) + ((a4 + a5) + (a6 + a7));
    }
    for (; base < total; ++base)
        acc += Ssc[(size_t)lst[base] * 128 + t];

    out[(size_t)i * 128 + t] = acc * dis[i] + bias[t];
}

extern "C" void kernel_launch(void* const* d_in, const int* in_sizes, int n_in,
                              void* d_out, int out_size, void* d_ws, size_t ws_size,
                              hipStream_t stream) {
    const float* x        = (const float*)d_in[0];
    const int*   ei       = (const int*)d_in[1];
    const float* ln_gamma = (const float*)d_in[2];
    const float* ln_beta  = (const float*)d_in[3];
    const float* spline_w = (const float*)d_in[4];
    const float* base_w   = (const float*)d_in[5];
    const float* base_b   = (const float*)d_in[6];
    const float* bias     = (const float*)d_in[7];
    float* out = (float*)d_out;

    char* ws = (char*)d_ws;
    const size_t BM_OFF  = 0;                      // 33,554,432 B
    const size_t WT_OFF  = 33554432;               // 589,824 B
    const size_t DIS_OFF = 34144256;               // 65,536 B
    const size_t SSC_OFF = 34209792;               // 8,388,608 B
    const size_t NEEDED  = 42598400;
    if (ws_size < NEEDED) return;                  // insufficient scratch

    uint32* bm  = (uint32*)(ws + BM_OFF);
    float*  Wt  = (float*)(ws + WT_OFF);
    float*  dis = (float*)(ws + DIS_OFF);
    float*  Ssc = (float*)(ws + SSC_OFF);

    hipMemsetAsync(bm, 0, (size_t)N_NODES * WORDS * 4, stream);
    transw_kernel<<<576, 256, 0, stream>>>(spline_w, base_w, Wt);
    scatter_kernel<<<NE / 256, 256, 0, stream>>>(ei, bm);
    deg_kernel<<<N_NODES / 4, 256, 0, stream>>>(bm, dis);
    support_kernel<<<N_NODES / 8, 128, 0, stream>>>(x, ln_gamma, ln_beta, Wt,
                                                    base_b, dis, Ssc);
    aggregate_kernel<<<N_NODES, 128, 0, stream>>>(bm, Ssc, dis, bias, out);
}

// Round 2
// 111.473 us; speedup vs baseline: 2.3470x; 2.3470x over previous
//
#include <hip/hip_runtime.h>

#define N_NODES 16384
#define NE 524288
#define WORDS 512          // 16384 bits / 32 per row
#define KDIM 1152          // IN*NG + IN
#define KSTEPS 36          // 1152 / 32

typedef unsigned int uint32;
typedef unsigned short ushort;
typedef __attribute__((ext_vector_type(8))) short bf16x8;
typedef __attribute__((ext_vector_type(4))) float f32x4;

__device__ __forceinline__ ushort f2bf(float f) {
    unsigned u = __float_as_uint(f);
    unsigned r = (u + 0x7fffu + ((u >> 16) & 1u)) >> 16;
    return (ushort)r;
}
__device__ __forceinline__ float bflo(uint32 u) {
    return __uint_as_float(u << 16);
}
__device__ __forceinline__ float bfhi(uint32 u) {
    return __uint_as_float(u & 0xffff0000u);
}

// ---------------- weight pack into MFMA B-fragment order (bf16) ----------------
// Wp[((kk*8 + ct)*64 + lane)*8 + i] = W[k][col],
//   k = kk*32 + (lane>>4)*8 + i, col = ct*16 + (lane&15)
//   W[k][col] = k<1024 ? spline_w[col*1024+k] : base_w[col*128+(k-1024)]
__global__ __launch_bounds__(256) void transw_kernel(
    const float* __restrict__ sw, const float* __restrict__ bw,
    ushort* __restrict__ Wp) {
    int idx = blockIdx.x * 256 + threadIdx.x;      // 0 .. 147455
    int i  = idx & 7;
    int l  = (idx >> 3) & 63;
    int ct = (idx >> 9) & 7;
    int kk = idx >> 12;
    int k   = kk * 32 + ((l >> 4) << 3) + i;
    int col = ct * 16 + (l & 15);
    float v = (k < 1024) ? sw[col * 1024 + k] : bw[col * 128 + (k - 1024)];
    Wp[idx] = f2bf(v);
}

// ---------------- edge scatter into bitmask ----------------
__global__ __launch_bounds__(256) void scatter_kernel(
    const int* __restrict__ ei, uint32* __restrict__ bm) {
    int e = blockIdx.x * 256 + threadIdx.x;
    int a = ei[e];
    int b = ei[NE + e];
    atomicOr(bm + (size_t)a * WORDS + (b >> 5), 1u << (b & 31));
    atomicOr(bm + (size_t)b * WORDS + (a >> 5), 1u << (a & 31));
}

// ---------------- degree -> dis = rsqrt(deg) ----------------
__global__ __launch_bounds__(256) void deg_kernel(
    const uint32* __restrict__ bm, float* __restrict__ dis) {
    const int lane = threadIdx.x & 63;
    const int row = blockIdx.x * 4 + (threadIdx.x >> 6);
    const uint32* r = bm + (size_t)row * WORDS;
    int s = 0;
#pragma unroll
    for (int q = 0; q < 8; ++q) s += __popc(r[lane + 64 * q]);
#pragma unroll
    for (int o = 32; o; o >>= 1) s += __shfl_xor(s, o);
    if (lane == 0) dis[row] = rsqrtf((float)s);
}

// ---------------- fused FastKAN support (bf16 MFMA), pre-scaled by dis ----------------
// block = 256 threads (4 waves), 16 nodes per block
// wave w: basis for nodes w*4..w*4+3; GEMM col-tiles {2w, 2w+1}
__global__ __launch_bounds__(256) void support_kernel(
    const float* __restrict__ x, const float* __restrict__ gamma,
    const float* __restrict__ beta, const ushort* __restrict__ Wp,
    const float* __restrict__ base_b, const float* __restrict__ dis,
    ushort* __restrict__ Ssc) {
    __shared__ ushort Bs[16][KDIM];                 // 36864 B
    const int t = threadIdx.x;
    const int lane = t & 63;
    const int w = t >> 6;
    const int nodeBase = blockIdx.x * 16;

    const float g0 = gamma[lane], g1 = gamma[lane + 64];
    const float be0 = beta[lane], be1 = beta[lane + 64];

    for (int n = w * 4; n < w * 4 + 4; ++n) {
        const int row = nodeBase + n;
        float f0 = x[(size_t)row * 128 + lane];
        float f1 = x[(size_t)row * 128 + lane + 64];
        float s = f0 + f1;
#pragma unroll
        for (int o = 32; o; o >>= 1) s += __shfl_xor(s, o);
        float mu = s * 0.0078125f;
        float d0 = f0 - mu, d1 = f1 - mu;
        float v = d0 * d0 + d1 * d1;
#pragma unroll
        for (int o = 32; o; o >>= 1) v += __shfl_xor(v, o);
        float rstd = rsqrtf(v * 0.0078125f + 1e-5f);
        float h0 = d0 * rstd * g0 + be0;
        float h1 = d1 * rstd * g1 + be1;
        ushort pk0[8] __attribute__((aligned(16)));
        ushort pk1[8] __attribute__((aligned(16)));
#pragma unroll
        for (int g = 0; g < 8; ++g) {
            float gv = -2.0f + (float)g * (4.0f / 7.0f);
            float z0 = (h0 - gv) * 1.75f;
            float z1 = (h1 - gv) * 1.75f;
            pk0[g] = f2bf(__expf(-z0 * z0));
            pk1[g] = f2bf(__expf(-z1 * z1));
        }
        *reinterpret_cast<uint4*>(&Bs[n][lane * 8]) =
            *reinterpret_cast<const uint4*>(pk0);
        *reinterpret_cast<uint4*>(&Bs[n][(lane + 64) * 8]) =
            *reinterpret_cast<const uint4*>(pk1);
        Bs[n][1024 + lane]      = f2bf(f0 / (1.0f + __expf(-f0)));
        Bs[n][1024 + lane + 64] = f2bf(f1 / (1.0f + __expf(-f1)));
    }
    __syncthreads();

    // GEMM: A = Bs (16 x 1152), B = Wp (1152 x 128), wave w -> cols w*32..w*32+31
    const int ct0 = w * 2;
    f32x4 acc0 = {0.f, 0.f, 0.f, 0.f};
    f32x4 acc1 = {0.f, 0.f, 0.f, 0.f};
    const ushort* ArowBase = &Bs[lane & 15][(lane >> 4) * 8];
    const bf16x8* Wv = (const bf16x8*)Wp;
#pragma unroll 4
    for (int kk = 0; kk < KSTEPS; ++kk) {
        bf16x8 a = *reinterpret_cast<const bf16x8*>(ArowBase + kk * 32);
        bf16x8 b0 = Wv[(size_t)(kk * 8 + ct0) * 64 + lane];
        bf16x8 b1 = Wv[(size_t)(kk * 8 + ct0 + 1) * 64 + lane];
        acc0 = __builtin_amdgcn_mfma_f32_16x16x32_bf16(a, b0, acc0, 0, 0, 0);
        acc1 = __builtin_amdgcn_mfma_f32_16x16x32_bf16(a, b1, acc1, 0, 0, 0);
    }

    // epilogue: C/D layout col = lane&15, row = (lane>>4)*4 + reg
    const int col0 = ct0 * 16 + (lane & 15);
    const int rbase = (lane >> 4) * 4;
    const float bb0 = base_b[col0];
    const float bb1 = base_b[col0 + 16];
#pragma unroll
    for (int r = 0; r < 4; ++r) {
        const int row = nodeBase + rbase + r;
        const float di = dis[row];
        Ssc[(size_t)row * 128 + col0]      = f2bf((acc0[r] + bb0) * di);
        Ssc[(size_t)row * 128 + col0 + 16] = f2bf((acc1[r] + bb1) * di);
    }
}

// ---------------- aggregation: out[i] = dis_i * sum Ssc[nbr] + bias ----------------
// block = 128 threads (2 waves); lane owns cols {2*lane, 2*lane+1}
__global__ __launch_bounds__(128) void aggregate_kernel(
    const uint32* __restrict__ bm, const ushort* __restrict__ Ssc,
    const float* __restrict__ dis, const float* __restrict__ bias,
    float* __restrict__ out) {
    __shared__ ushort lst[4096];
    __shared__ int cnts[128];
    __shared__ float part[2][128];
    const int t = threadIdx.x;
    const int i = blockIdx.x;

    uint4 w4 = ((const uint4*)(bm + (size_t)i * WORDS))[t];
    uint32 wsv[4] = {w4.x, w4.y, w4.z, w4.w};
    int myc = __popc(wsv[0]) + __popc(wsv[1]) + __popc(wsv[2]) + __popc(wsv[3]);
    cnts[t] = myc;
    __syncthreads();
#pragma unroll
    for (int off = 1; off < 128; off <<= 1) {
        int v = cnts[t];
        int add = (t >= off) ? cnts[t - off] : 0;
        __syncthreads();
        cnts[t] = v + add;
        __syncthreads();
    }
    int start = cnts[t] - myc;
    int total = cnts[127];
    if (total > 4096) total = 4096;

    int pos = start;
#pragma unroll
    for (int q = 0; q < 4; ++q) {
        uint32 wbits = wsv[q];
        int cbase = t * 128 + q * 32;
        while (wbits) {
            int b = __ffs(wbits) - 1;
            wbits &= wbits - 1;
            if (pos < 4096) lst[pos] = (ushort)(cbase + b);
            ++pos;
        }
    }
    __syncthreads();

    const int lane = t & 63;
    const int wv = t >> 6;
    const uint32* S32 = (const uint32*)Ssc;          // row stride 64 uints
    float a0 = 0.f, a1 = 0.f;
    int idx = wv;
    for (; idx + 6 < total; idx += 8) {
        int j0 = lst[idx], j1 = lst[idx + 2], j2 = lst[idx + 4], j3 = lst[idx + 6];
        uint32 u0 = S32[(size_t)j0 * 64 + lane];
        uint32 u1 = S32[(size_t)j1 * 64 + lane];
        uint32 u2 = S32[(size_t)j2 * 64 + lane];
        uint32 u3 = S32[(size_t)j3 * 64 + lane];
        a0 += (bflo(u0) + bflo(u1)) + (bflo(u2) + bflo(u3));
        a1 += (bfhi(u0) + bfhi(u1)) + (bfhi(u2) + bfhi(u3));
    }
    for (; idx < total; idx += 2) {
        uint32 u = S32[(size_t)lst[idx] * 64 + lane];
        a0 += bflo(u);
        a1 += bfhi(u);
    }
    part[wv][lane * 2]     = a0;
    part[wv][lane * 2 + 1] = a1;
    __syncthreads();

    float v = part[0][t] + part[1][t];
    out[(size_t)i * 128 + t] = v * dis[i] + bias[t];
}

extern "C" void kernel_launch(void* const* d_in, const int* in_sizes, int n_in,
                              void* d_out, int out_size, void* d_ws, size_t ws_size,
                              hipStream_t stream) {
    const float* x        = (const float*)d_in[0];
    const int*   ei       = (const int*)d_in[1];
    const float* ln_gamma = (const float*)d_in[2];
    const float* ln_beta  = (const float*)d_in[3];
    const float* spline_w = (const float*)d_in[4];
    const float* base_w   = (const float*)d_in[5];
    const float* base_b   = (const float*)d_in[6];
    const float* bias     = (const float*)d_in[7];
    float* out = (float*)d_out;

    char* ws = (char*)d_ws;
    const size_t BM_OFF  = 0;                       // 33,554,432 B
    const size_t WP_OFF  = 33554432;                // 294,912 B (bf16 packed W)
    const size_t DIS_OFF = 33849344;                // 65,536 B
    const size_t SSC_OFF = 33914880;                // 4,194,304 B (bf16)
    const size_t NEEDED  = 38109184;
    if (ws_size < NEEDED) return;

    uint32* bm  = (uint32*)(ws + BM_OFF);
    ushort* Wp  = (ushort*)(ws + WP_OFF);
    float*  dis = (float*)(ws + DIS_OFF);
    ushort* Ssc = (ushort*)(ws + SSC_OFF);

    hipMemsetAsync(bm, 0, (size_t)N_NODES * WORDS * 4, stream);
    transw_kernel<<<576, 256, 0, stream>>>(spline_w, base_w, Wp);
    scatter_kernel<<<NE / 256, 256, 0, stream>>>(ei, bm);
    deg_kernel<<<N_NODES / 4, 256, 0, stream>>>(bm, dis);
    support_kernel<<<N_NODES / 16, 256, 0, stream>>>(x, ln_gamma, ln_beta, Wp,
                                                     base_b, dis, Ssc);
    aggregate_kernel<<<N_NODES, 128, 0, stream>>>(bm, Ssc, dis, bias, out);
}